// Round 1
// baseline (211.084 us; speedup 1.0000x reference)
//
#include <hip/hip_runtime.h>

// PositionalEncoder: out[k] = sum_j ((1 - j/J) - (k/d)*(1 - 2j/J)) * E[j,k]
// j = 1..J (row+1), k = 1..d (col+1). E row-major [J, D] fp32.
//
// R8 = R7 with stage2+stage3 fused into one kernel (pe_reduce), with
// BIT-IDENTICAL reduction order to the old pair (absmax must stay 0.0):
//   p2[b2][k] = sum_{r=0..15} ws[16*b2 + r][k]          (sequential adds)
//   out[k]    = (s0+s1)+(s2+s3), s_i = sum_m p2[4m+i][k] (m ascending)
// Theory: timed region = harness reset (~2x512MiB fills ~156us, fixed) +
// our kernels (~25us, near the 128MiB read floor). Fusion shaves one
// dispatch + stage3 exec (~3-5us); if dur stays ~181 the session is
// reset-bound and we are at the effective roofline.

constexpr int D_COLS = 2048;
constexpr int J_ROWS = 16384;
constexpr int T1  = 512;            // 512 threads x float4 spans one full row
constexpr int NB1 = 1024;           // stage-1 blocks; 32 waves/CU
constexpr int NBR = 32;             // reduce blocks: 32 x 64 cols = 2048

typedef float vfloat4 __attribute__((ext_vector_type(4)));

__global__ __launch_bounds__(T1, 8) void pe_stage1(const float* __restrict__ E,
                                                   float* __restrict__ ws) {
    const int tid  = threadIdx.x;
    const int col0 = tid * 4;
    const int b    = blockIdx.x;
    const float invJ = 1.0f / (float)J_ROWS;
    const float invD = 1.0f / (float)D_COLS;
    const float c0 = (float)(col0 + 1) * invD;
    const float c1 = (float)(col0 + 2) * invD;
    const float c2 = (float)(col0 + 3) * invD;
    const float c3 = (float)(col0 + 4) * invD;

    float ax = 0.f, ay = 0.f, az = 0.f, aw = 0.f;
    // Sweep: per iteration the WHOLE GRID covers rows [it*4096, it*4096+4096)
    // contiguously; block b owns 4 adjacent rows inside that window.
    #pragma unroll 1
    for (int it = 0; it < J_ROWS / (4 * NB1); ++it) {   // 4 iterations
        const int r0 = (it * NB1 + b) * 4;
        const float* base = E + (size_t)r0 * D_COLS + col0;
        const vfloat4 e0 = __builtin_nontemporal_load(
            reinterpret_cast<const vfloat4*>(base + (size_t)0 * D_COLS));
        const vfloat4 e1 = __builtin_nontemporal_load(
            reinterpret_cast<const vfloat4*>(base + (size_t)1 * D_COLS));
        const vfloat4 e2 = __builtin_nontemporal_load(
            reinterpret_cast<const vfloat4*>(base + (size_t)2 * D_COLS));
        const vfloat4 e3 = __builtin_nontemporal_load(
            reinterpret_cast<const vfloat4*>(base + (size_t)3 * D_COLS));

        const float j0 = (float)(r0 + 1);
        const float j1 = j0 + 1.0f, j2 = j0 + 2.0f, j3 = j0 + 3.0f;
        const float a0 = fmaf(-j0, invJ, 1.0f), bb0 = fmaf(-2.f * j0, invJ, 1.0f);
        const float a1 = fmaf(-j1, invJ, 1.0f), bb1 = fmaf(-2.f * j1, invJ, 1.0f);
        const float a2 = fmaf(-j2, invJ, 1.0f), bb2 = fmaf(-2.f * j2, invJ, 1.0f);
        const float a3 = fmaf(-j3, invJ, 1.0f), bb3 = fmaf(-2.f * j3, invJ, 1.0f);

        ax = fmaf(fmaf(-c0, bb0, a0), e0.x, ax);
        ay = fmaf(fmaf(-c1, bb0, a0), e0.y, ay);
        az = fmaf(fmaf(-c2, bb0, a0), e0.z, az);
        aw = fmaf(fmaf(-c3, bb0, a0), e0.w, aw);
        ax = fmaf(fmaf(-c0, bb1, a1), e1.x, ax);
        ay = fmaf(fmaf(-c1, bb1, a1), e1.y, ay);
        az = fmaf(fmaf(-c2, bb1, a1), e1.z, az);
        aw = fmaf(fmaf(-c3, bb1, a1), e1.w, aw);
        ax = fmaf(fmaf(-c0, bb2, a2), e2.x, ax);
        ay = fmaf(fmaf(-c1, bb2, a2), e2.y, ay);
        az = fmaf(fmaf(-c2, bb2, a2), e2.z, az);
        aw = fmaf(fmaf(-c3, bb2, a2), e2.w, aw);
        ax = fmaf(fmaf(-c0, bb3, a3), e3.x, ax);
        ay = fmaf(fmaf(-c1, bb3, a3), e3.y, ay);
        az = fmaf(fmaf(-c2, bb3, a3), e3.z, az);
        aw = fmaf(fmaf(-c3, bb3, a3), e3.w, aw);
    }

    // Row-major, float4-coalesced full-line store (R5 lesson: no scatter).
    vfloat4 acc; acc.x = ax; acc.y = ay; acc.z = az; acc.w = aw;
    *reinterpret_cast<vfloat4*>(ws + (size_t)b * D_COLS + col0) = acc;
}

// Fused stage2+3. Block b owns 64 columns [64b, 64b+64). 512 threads =
// 8 row-groups x 64 cols; wave w == group g (lanes = consecutive cols ->
// every global load is a contiguous 256B segment; LDS accesses conflict-free:
// write = consecutive cols per wave, read = 2 lanes/bank broadcast-free).
__global__ __launch_bounds__(T1) void pe_reduce(const float* __restrict__ ws,
                                                float* __restrict__ out) {
    const int t = threadIdx.x;
    const int g = t >> 6;              // 0..7: owns p2 indices [8g, 8g+8)
    const int c = t & 63;              // col within block
    const int col = blockIdx.x * 64 + c;
    __shared__ float lds[64][64];      // [p2 index][col] = 16 KB

    const float* base = ws + (size_t)(g * 8 * 16) * D_COLS + col;
    #pragma unroll
    for (int i = 0; i < 8; ++i) {      // 8 independent 16-add chains (ILP=8)
        float a = 0.f;
        #pragma unroll
        for (int r = 0; r < 16; ++r) { // sequential: matches old stage2 order
            a += base[(size_t)(i * 16 + r) * D_COLS];
        }
        lds[g * 8 + i][c] = a;
    }
    __syncthreads();

    if (t < 64) {                      // matches old stage3 order exactly
        float s0 = 0.f, s1 = 0.f, s2 = 0.f, s3 = 0.f;
        #pragma unroll
        for (int r = 0; r < 64; r += 4) {
            s0 += lds[r + 0][t];
            s1 += lds[r + 1][t];
            s2 += lds[r + 2][t];
            s3 += lds[r + 3][t];
        }
        out[blockIdx.x * 64 + t] = (s0 + s1) + (s2 + s3);
    }
}

extern "C" void kernel_launch(void* const* d_in, const int* in_sizes, int n_in,
                              void* d_out, int out_size, void* d_ws, size_t ws_size,
                              hipStream_t stream) {
    const float* E = (const float*)d_in[0];
    float* out = (float*)d_out;
    float* ws  = (float*)d_ws;                          // 8 MiB partials
    (void)in_sizes; (void)n_in; (void)out_size; (void)ws_size;

    pe_stage1<<<NB1, T1, 0, stream>>>(E, ws);
    pe_reduce<<<NBR, T1, 0, stream>>>(ws, out);
}

// Round 2
// 184.502 us; speedup vs baseline: 1.1441x; 1.1441x over previous
//
#include <hip/hip_runtime.h>

// PositionalEncoder: out[k] = sum_j ((1 - j/J) - (k/d)*(1 - 2j/J)) * E[j,k]
// j = 1..J (row+1), k = 1..d (col+1). E row-major [J, D] fp32.
//
// R9 = exact revert to R7 (the 182.4 us three-kernel version).
// Purpose: A/B discriminator after R8's fused-reduce regressed to 211 us.
//   ~182 here  -> env stable; R8's pe_reduce was genuinely ~-29 us (256B/wave
//                 strided loads on a 32-block grid, latency-bound); R7 is the
//                 effective roofline (reset fills ~156us + 21us E-read + ~4us).
//   ~211 here  -> environment drift; re-evaluate baseline in-session.
//
// Stage structure (proven): sweep-ordered stage1 (whole grid covers one
// contiguous 32 MiB row-window per iteration, nontemporal float4 loads),
// then ws[1024][2048] -> ws2[64][2048] -> out[2048], all float4-coalesced.

constexpr int D_COLS = 2048;
constexpr int J_ROWS = 16384;
constexpr int T1  = 512;            // 512 threads x float4 spans one full row
constexpr int NB1 = 1024;           // stage-1 blocks; 32 waves/CU
constexpr int NB2 = 64;             // stage-2 blocks

typedef float vfloat4 __attribute__((ext_vector_type(4)));

__global__ __launch_bounds__(T1, 8) void pe_stage1(const float* __restrict__ E,
                                                   float* __restrict__ ws) {
    const int tid  = threadIdx.x;
    const int col0 = tid * 4;
    const int b    = blockIdx.x;
    const float invJ = 1.0f / (float)J_ROWS;
    const float invD = 1.0f / (float)D_COLS;
    const float c0 = (float)(col0 + 1) * invD;
    const float c1 = (float)(col0 + 2) * invD;
    const float c2 = (float)(col0 + 3) * invD;
    const float c3 = (float)(col0 + 4) * invD;

    float ax = 0.f, ay = 0.f, az = 0.f, aw = 0.f;
    // Sweep: per iteration the WHOLE GRID covers rows [it*4096, it*4096+4096)
    // contiguously; block b owns 4 adjacent rows inside that window.
    #pragma unroll 1
    for (int it = 0; it < J_ROWS / (4 * NB1); ++it) {   // 4 iterations
        const int r0 = (it * NB1 + b) * 4;
        const float* base = E + (size_t)r0 * D_COLS + col0;
        const vfloat4 e0 = __builtin_nontemporal_load(
            reinterpret_cast<const vfloat4*>(base + (size_t)0 * D_COLS));
        const vfloat4 e1 = __builtin_nontemporal_load(
            reinterpret_cast<const vfloat4*>(base + (size_t)1 * D_COLS));
        const vfloat4 e2 = __builtin_nontemporal_load(
            reinterpret_cast<const vfloat4*>(base + (size_t)2 * D_COLS));
        const vfloat4 e3 = __builtin_nontemporal_load(
            reinterpret_cast<const vfloat4*>(base + (size_t)3 * D_COLS));

        const float j0 = (float)(r0 + 1);
        const float j1 = j0 + 1.0f, j2 = j0 + 2.0f, j3 = j0 + 3.0f;
        const float a0 = fmaf(-j0, invJ, 1.0f), bb0 = fmaf(-2.f * j0, invJ, 1.0f);
        const float a1 = fmaf(-j1, invJ, 1.0f), bb1 = fmaf(-2.f * j1, invJ, 1.0f);
        const float a2 = fmaf(-j2, invJ, 1.0f), bb2 = fmaf(-2.f * j2, invJ, 1.0f);
        const float a3 = fmaf(-j3, invJ, 1.0f), bb3 = fmaf(-2.f * j3, invJ, 1.0f);

        ax = fmaf(fmaf(-c0, bb0, a0), e0.x, ax);
        ay = fmaf(fmaf(-c1, bb0, a0), e0.y, ay);
        az = fmaf(fmaf(-c2, bb0, a0), e0.z, az);
        aw = fmaf(fmaf(-c3, bb0, a0), e0.w, aw);
        ax = fmaf(fmaf(-c0, bb1, a1), e1.x, ax);
        ay = fmaf(fmaf(-c1, bb1, a1), e1.y, ay);
        az = fmaf(fmaf(-c2, bb1, a1), e1.z, az);
        aw = fmaf(fmaf(-c3, bb1, a1), e1.w, aw);
        ax = fmaf(fmaf(-c0, bb2, a2), e2.x, ax);
        ay = fmaf(fmaf(-c1, bb2, a2), e2.y, ay);
        az = fmaf(fmaf(-c2, bb2, a2), e2.z, az);
        aw = fmaf(fmaf(-c3, bb2, a2), e2.w, aw);
        ax = fmaf(fmaf(-c0, bb3, a3), e3.x, ax);
        ay = fmaf(fmaf(-c1, bb3, a3), e3.y, ay);
        az = fmaf(fmaf(-c2, bb3, a3), e3.z, az);
        aw = fmaf(fmaf(-c3, bb3, a3), e3.w, aw);
    }

    // Row-major, float4-coalesced full-line store (R5 lesson: no scatter).
    vfloat4 acc; acc.x = ax; acc.y = ay; acc.z = az; acc.w = aw;
    *reinterpret_cast<vfloat4*>(ws + (size_t)b * D_COLS + col0) = acc;
}

// stage2: block b sums ws rows [16b, 16b+16) -> ws2[b][*]. All coalesced.
__global__ __launch_bounds__(T1) void pe_stage2(const float* __restrict__ ws,
                                                float* __restrict__ ws2) {
    const int col0 = threadIdx.x * 4;
    const int b    = blockIdx.x;
    const float* base = ws + (size_t)(b * (NB1 / NB2)) * D_COLS + col0;
    vfloat4 acc = (vfloat4)0.f;
    #pragma unroll
    for (int r = 0; r < NB1 / NB2; ++r) {
        const vfloat4 v = *reinterpret_cast<const vfloat4*>(base + (size_t)r * D_COLS);
        acc += v;
    }
    *reinterpret_cast<vfloat4*>(ws2 + (size_t)b * D_COLS + col0) = acc;
}

// stage3: thread k sums ws2[r][k], r=0..63 (L2-hot, 4-way ILP). Writes out.
__global__ __launch_bounds__(T1) void pe_stage3(const float* __restrict__ ws2,
                                                float* __restrict__ out) {
    const int k = blockIdx.x * T1 + threadIdx.x;
    float s0 = 0.f, s1 = 0.f, s2 = 0.f, s3 = 0.f;
    #pragma unroll
    for (int r = 0; r < NB2; r += 4) {
        s0 += ws2[(size_t)(r + 0) * D_COLS + k];
        s1 += ws2[(size_t)(r + 1) * D_COLS + k];
        s2 += ws2[(size_t)(r + 2) * D_COLS + k];
        s3 += ws2[(size_t)(r + 3) * D_COLS + k];
    }
    out[k] = (s0 + s1) + (s2 + s3);
}

extern "C" void kernel_launch(void* const* d_in, const int* in_sizes, int n_in,
                              void* d_out, int out_size, void* d_ws, size_t ws_size,
                              hipStream_t stream) {
    const float* E = (const float*)d_in[0];
    float* out = (float*)d_out;
    float* ws  = (float*)d_ws;                          // 8 MiB partials
    float* ws2 = ws + (size_t)NB1 * D_COLS;             // +512 KB second level
    (void)in_sizes; (void)n_in; (void)out_size; (void)ws_size;

    pe_stage1<<<NB1, T1, 0, stream>>>(E, ws);
    pe_stage2<<<NB2, T1, 0, stream>>>(ws, ws2);
    pe_stage3<<<D_COLS / T1, T1, 0, stream>>>(ws2, out);
}